// Round 18
// baseline (209.014 us; speedup 1.0000x reference)
//
#include <hip/hip_runtime.h>
#include <hip/hip_bf16.h>

#define N_NODES 100000
#define FDIM 128
#define RREL 3
#define NEDGE 262144
#define SLOPE 0.2f
#define NCHUNK 98  // ceil(N_NODES/1024)
#define PROJ_BLOCKS 782                    // ceil(N_NODES/128)
#define HIST_BLOCKS (RREL * NEDGE / 256)   // 3072
#define NTILES 3125                        // N_NODES/32
#define AGG_XBLOCKS 6250                   // N_NODES/16
#define CAST_XBLOCKS 8                     // 8 x 3(y) blocks x 2048 = 49152

typedef __attribute__((ext_vector_type(8))) short bf16x8;
typedef __attribute__((ext_vector_type(8))) unsigned short u16x8;
typedef __attribute__((ext_vector_type(4))) float f32x4;
typedef __attribute__((ext_vector_type(16))) float f32x16;
typedef __attribute__((ext_vector_type(4))) int i32x4;

__device__ inline unsigned short f2bf(float f) {
    __hip_bfloat16 h = __float2bfloat16(f);
    return *reinterpret_cast<unsigned short*>(&h);
}
__device__ inline float bf2f(unsigned short u) {
    unsigned int b = ((unsigned int)u) << 16;
    return __int_as_float(b);
}

// -------- workspace layout (float units, 4 B each) --------
#define WS_PS    0          // R*N
#define WS_PD    300000     // R*N
#define WS_SUMS  600000     // 16 (slot 12 = scan done-counter; zeroed with count)
#define WS_COUNT 600016     // R*N  (histogram)
#define WS_ROWS  900016     // R*N  CSR row starts (chunk-local; bsum added by consumers)
#define WS_BSUM  1200016    // 512
#define WS_ESORT 1200528    // R*E int2 = 1572864 floats
#define WS_ASUM  2773392    // R*N
#define WS_TWT   3073392    // 49152 bf16 = 24576 floats (frag-ordered, inv-scaled tw)
#define WS_TBS   3097968    // 384 (inv-scaled tb)
#define WS_XBF   3098352    // N*128 bf16 = 6.4M floats
#define WS_AGGB  9498352    // N*384 bf16 = 19.2M floats
#define WS_RANK  28698352   // R*E ints

// fused kernel:
//  blocks [0, PROJ_BLOCKS): MFMA-based projections P = x @ [w_s|w_d] (6 cols)
//    + bf16 cast of x to x_bf.
//  blocks [PROJ_BLOCKS, +HIST_BLOCKS): dst histogram per relation, capturing
//    each edge's bucket rank from the atomic return.
__global__ __launch_bounds__(256, 4)
void proj_hist_kernel(const float* __restrict__ x,
                      const float* __restrict__ att_w,
                      float* __restrict__ ps, float* __restrict__ pd,
                      unsigned short* __restrict__ x_bf,
                      const int* __restrict__ dst, int* __restrict__ count,
                      int* __restrict__ rank) {
    if (blockIdx.x >= PROJ_BLOCKS) {
        const int b = blockIdx.x - PROJ_BLOCKS;
        const int gid = b * 256 + threadIdx.x;
        const int r = b >> 10;
        rank[gid] = atomicAdd(&count[r * N_NODES + dst[gid]], 1);
        return;
    }
    __shared__ unsigned short sX[128 * 136];  // 128 rows x (128 k + 8 pad)
    __shared__ unsigned short sW[16 * 136];   // 16 cols (6 valid) x 128 k
    const int tid = threadIdx.x;
    const int row0 = blockIdx.x * 128;

    // stage W: col c<3 -> w_s[c][k] = att_w[c*256+k]; c in 3..5 -> w_d[c-3][k]
#pragma unroll
    for (int i = 0; i < 8; ++i) {
        const int idx = tid + i * 256;
        const int c = idx >> 7, k = idx & 127;
        float v = 0.f;
        if (c < 3) v = att_w[c * 256 + k];
        else if (c < 6) v = att_w[(c - 3) * 256 + 128 + k];
        sW[c * 136 + k] = f2bf(v);
    }
    // stage X tile (bf16) + emit global x_bf
    const int g = tid >> 5, lane = tid & 31;
#pragma unroll
    for (int it = 0; it < 16; ++it) {
        const int rrow = it * 8 + g;
        const int row = row0 + rrow;
        float4 xv = make_float4(0.f, 0.f, 0.f, 0.f);
        if (row < N_NODES) xv = *reinterpret_cast<const float4*>(x + (size_t)row * FDIM + lane * 4);
        ushort4 u;
        u.x = f2bf(xv.x); u.y = f2bf(xv.y); u.z = f2bf(xv.z); u.w = f2bf(xv.w);
        if (row < N_NODES)
            *reinterpret_cast<ushort4*>(x_bf + (size_t)row * FDIM + lane * 4) = u;
        *reinterpret_cast<ushort4*>(&sX[rrow * 136 + lane * 4]) = u;
    }
    __syncthreads();

    const int w = tid >> 6, l = tid & 63;
    const int lr = l & 15, lk = l >> 4;
    f32x4 acc[2];
    acc[0] = (f32x4){0.f, 0.f, 0.f, 0.f};
    acc[1] = (f32x4){0.f, 0.f, 0.f, 0.f};
#pragma unroll
    for (int ks = 0; ks < 4; ++ks) {
        const bf16x8 bfr = *reinterpret_cast<const bf16x8*>(&sW[lr * 136 + ks * 32 + lk * 8]);
#pragma unroll
        for (int rt = 0; rt < 2; ++rt) {
            const bf16x8 afr =
                *reinterpret_cast<const bf16x8*>(&sX[(w * 32 + rt * 16 + lr) * 136 + ks * 32 + lk * 8]);
            acc[rt] = __builtin_amdgcn_mfma_f32_16x16x32_bf16(afr, bfr, acc[rt], 0, 0, 0);
        }
    }
    // epilogue: D row = (lane>>4)*4 + reg, col = lane&15; cols 0..2 -> ps, 3..5 -> pd
    if (lr < 6) {
        float* base = (lr < 3) ? (ps + lr * N_NODES) : (pd + (lr - 3) * N_NODES);
#pragma unroll
        for (int rt = 0; rt < 2; ++rt) {
            const int rowbase = row0 + w * 32 + rt * 16 + lk * 4;
#pragma unroll
            for (int j = 0; j < 4; ++j) {
                const int row = rowbase + j;
                if (row < N_NODES) base[row] = acc[rt][j];
            }
        }
    }
}

// ---- chunk-local prefix scan of count -> row_start; bsum = per-chunk totals.
//      The LAST block (device-scope counter) performs the 98-element exclusive
//      scan of bsum for all relations inline (replaces scan2_kernel).
__global__ void scan1_kernel(const int* __restrict__ count, int* __restrict__ row_start,
                             int* __restrict__ bsum, int* __restrict__ done) {
    const int r = blockIdx.x / NCHUNK;
    const int b = blockIdx.x % NCHUNK;
    const int tid = threadIdx.x;
    const int base = b * 1024 + tid * 4;
    int v[4];
#pragma unroll
    for (int i = 0; i < 4; ++i)
        v[i] = (base + i < N_NODES) ? count[r * N_NODES + base + i] : 0;
    const int tsum = v[0] + v[1] + v[2] + v[3];
    __shared__ int sd[256];
    sd[tid] = tsum;
    __syncthreads();
    for (int off = 1; off < 256; off <<= 1) {
        const int tv = (tid >= off) ? sd[tid - off] : 0;
        __syncthreads();
        sd[tid] += tv;
        __syncthreads();
    }
    int run = sd[tid] - tsum;
#pragma unroll
    for (int i = 0; i < 4; ++i) {
        if (base + i < N_NODES) row_start[r * N_NODES + base + i] = run;
        run += v[i];
    }
    if (tid == 255) bsum[blockIdx.x] = sd[255];

    // last-block inline scan of bsum (all relations)
    __shared__ int sticket;
    __threadfence();
    __syncthreads();
    if (tid == 0) sticket = atomicAdd(done, 1);
    __syncthreads();
    if (sticket != RREL * NCHUNK - 1) return;
    __threadfence();  // acquire all bsum writes
#pragma unroll
    for (int rr = 0; rr < RREL; ++rr) {
        const int vv = (tid < NCHUNK) ? bsum[rr * NCHUNK + tid] : 0;
        sd[tid] = vv;
        __syncthreads();
        for (int off = 1; off < 256; off <<= 1) {
            const int tv = (tid >= off) ? sd[tid - off] : 0;
            __syncthreads();
            sd[tid] += tv;
            __syncthreads();
        }
        if (tid < NCHUNK) bsum[rr * NCHUNK + tid] = sd[tid] - vv;
        __syncthreads();
    }
}

// fused score + CSR fill, atomic-free: pos = row_start[d] + bsum[chunk(d)] + rank[e].
__global__ void fill_kernel(const int* __restrict__ src, const int* __restrict__ dst,
                            const float* __restrict__ ps, const float* __restrict__ pd,
                            const float* __restrict__ att_b,
                            const int* __restrict__ row_start, const int* __restrict__ bsum,
                            const int* __restrict__ rank,
                            int2* __restrict__ edge_sorted, float* __restrict__ sums) {
    const int gid = blockIdx.x * 256 + threadIdx.x;
    const int r = blockIdx.x >> 10;
    const int s = src[gid];
    const int d = dst[gid];
    float sc = ps[r * N_NODES + s] + pd[r * N_NODES + d] + att_b[r];
    sc = sc > 0.f ? sc : SLOPE * sc;
    const float ev = __expf(sc);
    const int pos = row_start[r * N_NODES + d] + bsum[r * NCHUNK + (d >> 10)] + rank[gid];
    int2 pk;
    pk.x = s;
    pk.y = __float_as_int(ev);
    edge_sorted[(size_t)r * NEDGE + pos] = pk;
    float v = ev;
#pragma unroll
    for (int off = 32; off >= 1; off >>= 1) v += __shfl_xor(v, off);
    __shared__ float red[4];
    if ((threadIdx.x & 63) == 0) red[threadIdx.x >> 6] = v;
    __syncthreads();
    if (threadIdx.x == 0) {
        unsafeAtomicAdd(&sums[r], red[0] + red[1] + red[2] + red[3]);
    }
}

// FUSED agg + cast:
//  blocks with x < AGG_XBLOCKS (all y): CSR gather of bf16 x ->
//    aggb[n][r*128+f] = bf16( sum_e ev_e * x_bf[src_e][f] ); asum[r][n] = sum_e ev_e.
//  blocks with x >= AGG_XBLOCKS: emit tw in MFMA-fragment order (inv-scaled):
//    o = ks*4096 + kk*2048 + ct*512 + lane*8 + elem;
//    col = ct*32+(lane&31); k = ks*32 + kk*16 + (lane>>5)*8 + elem.
__global__ __launch_bounds__(256, 8)
void agg_kernel(const int* __restrict__ row_start, const int* __restrict__ bsum,
                const int2* __restrict__ edge_sorted,
                const unsigned short* __restrict__ x_bf,
                unsigned short* __restrict__ aggb, float* __restrict__ asum,
                const float* __restrict__ tw, const float* __restrict__ tb,
                const float* __restrict__ sums,
                unsigned short* __restrict__ twT, float* __restrict__ tbs) {
    const int tid = threadIdx.x;
    if (blockIdx.x >= AGG_XBLOCKS) {
        const int idx = (blockIdx.x - AGG_XBLOCKS) * RREL + blockIdx.y;  // 0..23
#pragma unroll
        for (int i = 0; i < 8; ++i) {
            const int o = idx * 2048 + i * 256 + tid;  // 0..49151
            const int elem = o & 7;
            const int lane = (o >> 3) & 63;
            const int ct   = (o >> 9) & 3;
            const int kk   = (o >> 11) & 1;
            const int ks   = o >> 12;
            const int col = ct * 32 + (lane & 31);
            const int k   = ks * 32 + kk * 16 + ((lane >> 5) << 3) + elem;
            const float inv = 1.0f / sums[k >> 7];
            twT[o] = f2bf(tw[k * 128 + col] * inv);
            if (o < 384) tbs[o] = tb[o] * (1.0f / sums[o >> 7]);
        }
        return;
    }
    const int lane = tid & 15;
    const int r = blockIdx.y;
    const int n = blockIdx.x * 16 + (tid >> 4);
    const int beg = row_start[r * N_NODES + n] + bsum[r * NCHUNK + (n >> 10)];
    const int end = (n == N_NODES - 1)
                        ? NEDGE
                        : row_start[r * N_NODES + n + 1] + bsum[r * NCHUNK + ((n + 1) >> 10)];
    const long long* es = (const long long*)(edge_sorted + (size_t)r * NEDGE);

    float acc[8] = {0.f, 0.f, 0.f, 0.f, 0.f, 0.f, 0.f, 0.f};
    float asacc = 0.f;

    for (int i = beg; i < end; i += 4) {
        const int rem = end - i;
        long long q0, q1, q2, q3;
        q0 = __builtin_nontemporal_load(es + i);
        if (rem > 1) q1 = __builtin_nontemporal_load(es + i + 1);
        if (rem > 2) q2 = __builtin_nontemporal_load(es + i + 2);
        if (rem > 3) q3 = __builtin_nontemporal_load(es + i + 3);
        u16x8 xv0, xv1, xv2, xv3;
        xv0 = *reinterpret_cast<const u16x8*>(x_bf + (size_t)(int)q0 * FDIM + lane * 8);
        if (rem > 1) xv1 = *reinterpret_cast<const u16x8*>(x_bf + (size_t)(int)q1 * FDIM + lane * 8);
        if (rem > 2) xv2 = *reinterpret_cast<const u16x8*>(x_bf + (size_t)(int)q2 * FDIM + lane * 8);
        if (rem > 3) xv3 = *reinterpret_cast<const u16x8*>(x_bf + (size_t)(int)q3 * FDIM + lane * 8);
        {
            const float a = __int_as_float((int)(q0 >> 32));
            asacc += a;
#pragma unroll
            for (int d = 0; d < 8; ++d) acc[d] += a * bf2f(xv0[d]);
        }
        if (rem > 1) {
            const float a = __int_as_float((int)(q1 >> 32));
            asacc += a;
#pragma unroll
            for (int d = 0; d < 8; ++d) acc[d] += a * bf2f(xv1[d]);
        }
        if (rem > 2) {
            const float a = __int_as_float((int)(q2 >> 32));
            asacc += a;
#pragma unroll
            for (int d = 0; d < 8; ++d) acc[d] += a * bf2f(xv2[d]);
        }
        if (rem > 3) {
            const float a = __int_as_float((int)(q3 >> 32));
            asacc += a;
#pragma unroll
            for (int d = 0; d < 8; ++d) acc[d] += a * bf2f(xv3[d]);
        }
    }

    u16x8 o;
#pragma unroll
    for (int d = 0; d < 8; ++d) o[d] = f2bf(acc[d]);
    i32x4* dst4 = reinterpret_cast<i32x4*>(aggb + (size_t)n * 384 + r * FDIM + lane * 8);
    __builtin_nontemporal_store(*reinterpret_cast<i32x4*>(&o), dst4);
    if (lane == 0) asum[r * N_NODES + n] = asacc;
}

// out[N][128] = relu( A[N][384](bf16) @ W + asum·tbs + h_bias )
// MFMA 32x32x16, barrier-free; full frag-ordered B (96 KB) in LDS.
// Grid = 256 (one block per CU); wave-major tile distribution.
// A-fragment loads for the first 4 K-steps are issued BEFORE the B-stage
// barrier so HBM/L3 latency hides under the LDS-write drain.
__global__ __launch_bounds__(1024, 4)
void gemm_kernel(const unsigned short* __restrict__ A, const unsigned short* __restrict__ Bf,
                 const float* __restrict__ asum, const float* __restrict__ tbs,
                 const float* __restrict__ h_bias, float* __restrict__ out) {
    __shared__ int4 sB[6144];  // 96 KB, frag-ordered: [ks][kk][ct][lane] x 16B
    const int tid = threadIdx.x;
    const int4* Bfv = reinterpret_cast<const int4*>(Bf);
#pragma unroll
    for (int i = 0; i < 6; ++i) sB[i * 1024 + tid] = Bfv[i * 1024 + tid];

    const int w = tid >> 6, l = tid & 63;
    const int t = w * 256 + blockIdx.x;  // tile id
    const bool active = t < NTILES;
    const int row = l & 31, hi = l >> 5;
    const int n0 = t * 32;
    const int arow = active ? (n0 + row) : 0;
    const unsigned short* aptr = A + (size_t)arow * 384 + hi * 8;

    // preload A frags for ks=0..3 before the barrier (hide B-stage drain)
    bf16x8 afr[8];
#pragma unroll
    for (int i = 0; i < 4; ++i) {
        afr[2 * i]     = *reinterpret_cast<const bf16x8*>(aptr + i * 32);
        afr[2 * i + 1] = *reinterpret_cast<const bf16x8*>(aptr + i * 32 + 16);
    }
    __syncthreads();
    if (!active) return;
    const unsigned short* sb = reinterpret_cast<const unsigned short*>(sB);

    f32x16 acc[4];
#pragma unroll
    for (int ct = 0; ct < 4; ++ct)
#pragma unroll
        for (int j = 0; j < 16; ++j) acc[ct][j] = 0.f;

#pragma unroll
    for (int ks = 0; ks < 12; ++ks) {
        const bf16x8 af0 = (ks < 4) ? afr[2 * ks]
                                    : *reinterpret_cast<const bf16x8*>(aptr + ks * 32);
        const bf16x8 af1 = (ks < 4) ? afr[2 * ks + 1]
                                    : *reinterpret_cast<const bf16x8*>(aptr + ks * 32 + 16);
        const unsigned short* sbk = sb + ks * 4096;
#pragma unroll
        for (int ct = 0; ct < 4; ++ct) {
            const bf16x8 b0 = *reinterpret_cast<const bf16x8*>(sbk + ct * 512 + l * 8);
            acc[ct] = __builtin_amdgcn_mfma_f32_32x32x16_bf16(af0, b0, acc[ct], 0, 0, 0);
        }
#pragma unroll
        for (int ct = 0; ct < 4; ++ct) {
            const bf16x8 b1 = *reinterpret_cast<const bf16x8*>(sbk + 2048 + ct * 512 + l * 8);
            acc[ct] = __builtin_amdgcn_mfma_f32_32x32x16_bf16(af1, b1, acc[ct], 0, 0, 0);
        }
    }

    // epilogue: D col = lane&31, row = (reg&3) + 8*(reg>>2) + 4*(lane>>5)
    const int col = row;  // l&31
    const float hb = h_bias[col];
    const float t0 = tbs[col], t1 = tbs[FDIM + col], t2 = tbs[2 * FDIM + col];
#pragma unroll
    for (int g = 0; g < 4; ++g) {
        const int rbase = n0 + g * 8 + hi * 4;
        float as0[4], as1[4], as2[4];
#pragma unroll
        for (int j = 0; j < 4; ++j) {
            as0[j] = asum[0 * N_NODES + rbase + j];
            as1[j] = asum[1 * N_NODES + rbase + j];
            as2[j] = asum[2 * N_NODES + rbase + j];
        }
#pragma unroll
        for (int ct = 0; ct < 4; ++ct) {
#pragma unroll
            for (int j = 0; j < 4; ++j) {
                const int r_ = rbase + j;
                float v = acc[ct][g * 4 + j] + as0[j] * t0 + as1[j] * t1 + as2[j] * t2 + hb;
                out[(size_t)r_ * FDIM + ct * 32 + col] = fmaxf(v, 0.f);
            }
        }
    }
}

extern "C" void kernel_launch(void* const* d_in, const int* in_sizes, int n_in,
                              void* d_out, int out_size, void* d_ws, size_t ws_size,
                              hipStream_t stream) {
    const float* x      = (const float*)d_in[0];
    const float* att_w  = (const float*)d_in[1];
    const float* att_b  = (const float*)d_in[2];
    const float* tw     = (const float*)d_in[3];
    const float* tb     = (const float*)d_in[4];
    const float* h_bias = (const float*)d_in[5];
    const int*   src    = (const int*)d_in[6];
    const int*   dst    = (const int*)d_in[7];
    float* out = (float*)d_out;

    float* wsf = (float*)d_ws;
    float* ps         = wsf + WS_PS;
    float* pd         = wsf + WS_PD;
    float* sums       = wsf + WS_SUMS;
    int*   done       = (int*)(wsf + WS_SUMS + 12);
    int*   count      = (int*)(wsf + WS_COUNT);
    int*   row_start  = (int*)(wsf + WS_ROWS);
    int*   bsum       = (int*)(wsf + WS_BSUM);
    int2*  edge_sorted= (int2*)(wsf + WS_ESORT);
    float* asum       = wsf + WS_ASUM;
    unsigned short* twT  = (unsigned short*)(wsf + WS_TWT);
    float* tbs        = wsf + WS_TBS;
    unsigned short* x_bf = (unsigned short*)(wsf + WS_XBF);
    unsigned short* aggb = (unsigned short*)(wsf + WS_AGGB);
    int*   rank       = (int*)(wsf + WS_RANK);

    // zero sums(16, incl. done-counter at slot 12) + count(R*N) in one shot
    hipMemsetAsync(sums, 0, (size_t)(16 + RREL * N_NODES) * sizeof(float), stream);

    proj_hist_kernel<<<PROJ_BLOCKS + HIST_BLOCKS, 256, 0, stream>>>(x, att_w, ps, pd, x_bf,
                                                                    dst, count, rank);

    scan1_kernel<<<RREL * NCHUNK, 256, 0, stream>>>(count, row_start, bsum, done);

    fill_kernel<<<RREL * NEDGE / 256, 256, 0, stream>>>(src, dst, ps, pd, att_b,
                                                        row_start, bsum, rank,
                                                        edge_sorted, sums);

    agg_kernel<<<dim3(AGG_XBLOCKS + CAST_XBLOCKS, RREL), 256, 0, stream>>>(
        row_start, bsum, edge_sorted, x_bf, aggb, asum, tw, tb, sums, twT, tbs);

    gemm_kernel<<<256, 1024, 0, stream>>>(aggb, twT, asum, tbs, h_bias, out);
}

// Round 19
// 182.204 us; speedup vs baseline: 1.1471x; 1.1471x over previous
//
#include <hip/hip_runtime.h>
#include <hip/hip_bf16.h>

#define N_NODES 100000
#define FDIM 128
#define RREL 3
#define NEDGE 262144
#define SLOPE 0.2f
#define NCHUNK 98  // ceil(N_NODES/1024)
#define PROJ_BLOCKS 782                    // ceil(N_NODES/128)
#define HIST_BLOCKS (RREL * NEDGE / 256)   // 3072
#define NTILES 3125                        // N_NODES/32

typedef __attribute__((ext_vector_type(8))) short bf16x8;
typedef __attribute__((ext_vector_type(8))) unsigned short u16x8;
typedef __attribute__((ext_vector_type(4))) float f32x4;
typedef __attribute__((ext_vector_type(16))) float f32x16;
typedef __attribute__((ext_vector_type(4))) int i32x4;

__device__ inline unsigned short f2bf(float f) {
    __hip_bfloat16 h = __float2bfloat16(f);
    return *reinterpret_cast<unsigned short*>(&h);
}
__device__ inline float bf2f(unsigned short u) {
    unsigned int b = ((unsigned int)u) << 16;
    return __int_as_float(b);
}

// -------- workspace layout (float units, 4 B each) --------
#define WS_PS    0          // R*N
#define WS_PD    300000     // R*N
#define WS_SUMS  600000     // 16
#define WS_COUNT 600016     // R*N  (histogram)
#define WS_ROWS  900016     // R*N  CSR row starts (chunk-local; bsum added by consumers)
#define WS_BSUM  1200016    // 512
#define WS_ESORT 1200528    // R*E int2 = 1572864 floats
#define WS_ASUM  2773392    // R*N
#define WS_TWT   3073392    // 49152 bf16 = 24576 floats (frag-ordered, inv-scaled tw)
#define WS_TBS   3097968    // 384 (inv-scaled tb)
#define WS_XBF   3098352    // N*128 bf16 = 6.4M floats
#define WS_AGGB  9498352    // N*384 bf16 = 19.2M floats
#define WS_RANK  28698352   // R*E ints

// fused kernel:
//  blocks [0, PROJ_BLOCKS): MFMA-based projections P = x @ [w_s|w_d] (6 cols)
//    + bf16 cast of x to x_bf.
//  blocks [PROJ_BLOCKS, +HIST_BLOCKS): dst histogram per relation, capturing
//    each edge's bucket rank from the atomic return.
__global__ __launch_bounds__(256, 4)
void proj_hist_kernel(const float* __restrict__ x,
                      const float* __restrict__ att_w,
                      float* __restrict__ ps, float* __restrict__ pd,
                      unsigned short* __restrict__ x_bf,
                      const int* __restrict__ dst, int* __restrict__ count,
                      int* __restrict__ rank) {
    if (blockIdx.x >= PROJ_BLOCKS) {
        const int b = blockIdx.x - PROJ_BLOCKS;
        const int gid = b * 256 + threadIdx.x;
        const int r = b >> 10;
        rank[gid] = atomicAdd(&count[r * N_NODES + dst[gid]], 1);
        return;
    }
    __shared__ unsigned short sX[128 * 136];  // 128 rows x (128 k + 8 pad)
    __shared__ unsigned short sW[16 * 136];   // 16 cols (6 valid) x 128 k
    const int tid = threadIdx.x;
    const int row0 = blockIdx.x * 128;

    // stage W: col c<3 -> w_s[c][k] = att_w[c*256+k]; c in 3..5 -> w_d[c-3][k]
#pragma unroll
    for (int i = 0; i < 8; ++i) {
        const int idx = tid + i * 256;
        const int c = idx >> 7, k = idx & 127;
        float v = 0.f;
        if (c < 3) v = att_w[c * 256 + k];
        else if (c < 6) v = att_w[(c - 3) * 256 + 128 + k];
        sW[c * 136 + k] = f2bf(v);
    }
    // stage X tile (bf16) + emit global x_bf
    const int g = tid >> 5, lane = tid & 31;
#pragma unroll
    for (int it = 0; it < 16; ++it) {
        const int rrow = it * 8 + g;
        const int row = row0 + rrow;
        float4 xv = make_float4(0.f, 0.f, 0.f, 0.f);
        if (row < N_NODES) xv = *reinterpret_cast<const float4*>(x + (size_t)row * FDIM + lane * 4);
        ushort4 u;
        u.x = f2bf(xv.x); u.y = f2bf(xv.y); u.z = f2bf(xv.z); u.w = f2bf(xv.w);
        if (row < N_NODES)
            *reinterpret_cast<ushort4*>(x_bf + (size_t)row * FDIM + lane * 4) = u;
        *reinterpret_cast<ushort4*>(&sX[rrow * 136 + lane * 4]) = u;
    }
    __syncthreads();

    const int w = tid >> 6, l = tid & 63;
    const int lr = l & 15, lk = l >> 4;
    f32x4 acc[2];
    acc[0] = (f32x4){0.f, 0.f, 0.f, 0.f};
    acc[1] = (f32x4){0.f, 0.f, 0.f, 0.f};
#pragma unroll
    for (int ks = 0; ks < 4; ++ks) {
        const bf16x8 bfr = *reinterpret_cast<const bf16x8*>(&sW[lr * 136 + ks * 32 + lk * 8]);
#pragma unroll
        for (int rt = 0; rt < 2; ++rt) {
            const bf16x8 afr =
                *reinterpret_cast<const bf16x8*>(&sX[(w * 32 + rt * 16 + lr) * 136 + ks * 32 + lk * 8]);
            acc[rt] = __builtin_amdgcn_mfma_f32_16x16x32_bf16(afr, bfr, acc[rt], 0, 0, 0);
        }
    }
    // epilogue: D row = (lane>>4)*4 + reg, col = lane&15; cols 0..2 -> ps, 3..5 -> pd
    if (lr < 6) {
        float* base = (lr < 3) ? (ps + lr * N_NODES) : (pd + (lr - 3) * N_NODES);
#pragma unroll
        for (int rt = 0; rt < 2; ++rt) {
            const int rowbase = row0 + w * 32 + rt * 16 + lk * 4;
#pragma unroll
            for (int j = 0; j < 4; ++j) {
                const int row = rowbase + j;
                if (row < N_NODES) base[row] = acc[rt][j];
            }
        }
    }
}

// ---- prefix scan of count -> row_start (chunk-local); bsum = per-chunk totals ----
__global__ void scan1_kernel(const int* __restrict__ count, int* __restrict__ row_start,
                             int* __restrict__ bsum) {
    const int r = blockIdx.x / NCHUNK;
    const int b = blockIdx.x % NCHUNK;
    const int tid = threadIdx.x;
    const int base = b * 1024 + tid * 4;
    int v[4];
#pragma unroll
    for (int i = 0; i < 4; ++i)
        v[i] = (base + i < N_NODES) ? count[r * N_NODES + base + i] : 0;
    const int tsum = v[0] + v[1] + v[2] + v[3];
    __shared__ int sd[256];
    sd[tid] = tsum;
    __syncthreads();
    for (int off = 1; off < 256; off <<= 1) {
        const int tv = (tid >= off) ? sd[tid - off] : 0;
        __syncthreads();
        sd[tid] += tv;
        __syncthreads();
    }
    int run = sd[tid] - tsum;
#pragma unroll
    for (int i = 0; i < 4; ++i) {
        if (base + i < N_NODES) row_start[r * N_NODES + base + i] = run;
        run += v[i];
    }
    if (tid == 255) bsum[blockIdx.x] = sd[255];
}

// exclusive scan of bsum per relation; also zeroes sums (runs before fill).
__global__ void scan2_kernel(int* __restrict__ bsum, float* __restrict__ sums) {
    const int r = blockIdx.x;
    const int tid = threadIdx.x;
    if (r == 0 && tid < 16) sums[tid] = 0.f;
    const int v = (tid < NCHUNK) ? bsum[r * NCHUNK + tid] : 0;
    __shared__ int sd[256];
    sd[tid] = v;
    __syncthreads();
    for (int off = 1; off < 256; off <<= 1) {
        const int tv = (tid >= off) ? sd[tid - off] : 0;
        __syncthreads();
        sd[tid] += tv;
        __syncthreads();
    }
    if (tid < NCHUNK) bsum[r * NCHUNK + tid] = sd[tid] - v;
}

// fused score + CSR fill, atomic-free: pos = row_start[d] + bsum[chunk(d)] + rank[e].
__global__ void fill_kernel(const int* __restrict__ src, const int* __restrict__ dst,
                            const float* __restrict__ ps, const float* __restrict__ pd,
                            const float* __restrict__ att_b,
                            const int* __restrict__ row_start, const int* __restrict__ bsum,
                            const int* __restrict__ rank,
                            int2* __restrict__ edge_sorted, float* __restrict__ sums) {
    const int gid = blockIdx.x * 256 + threadIdx.x;
    const int r = blockIdx.x >> 10;
    const int s = src[gid];
    const int d = dst[gid];
    float sc = ps[r * N_NODES + s] + pd[r * N_NODES + d] + att_b[r];
    sc = sc > 0.f ? sc : SLOPE * sc;
    const float ev = __expf(sc);
    const int pos = row_start[r * N_NODES + d] + bsum[r * NCHUNK + (d >> 10)] + rank[gid];
    int2 pk;
    pk.x = s;
    pk.y = __float_as_int(ev);
    edge_sorted[(size_t)r * NEDGE + pos] = pk;
    float v = ev;
#pragma unroll
    for (int off = 32; off >= 1; off >>= 1) v += __shfl_xor(v, off);
    __shared__ float red[4];
    if ((threadIdx.x & 63) == 0) red[threadIdx.x >> 6] = v;
    __syncthreads();
    if (threadIdx.x == 0) {
        unsafeAtomicAdd(&sums[r], red[0] + red[1] + red[2] + red[3]);
    }
}

// Emit tw in MFMA-fragment order for the 32x32x16 gemm, inv-scaled:
// o = ks*4096 + kk*2048 + ct*512 + lane*8 + elem
// col = ct*32 + (lane&31); k = ks*32 + kk*16 + (lane>>5)*8 + elem
__global__ void cast_kernel(const float* __restrict__ tw, const float* __restrict__ tb,
                            const float* __restrict__ sums,
                            unsigned short* __restrict__ twT, float* __restrict__ tbs) {
    const int o = blockIdx.x * 256 + threadIdx.x;  // 0..49151
    const int elem = o & 7;
    const int lane = (o >> 3) & 63;
    const int ct   = (o >> 9) & 3;
    const int kk   = (o >> 11) & 1;
    const int ks   = o >> 12;
    const int col = ct * 32 + (lane & 31);
    const int k   = ks * 32 + kk * 16 + ((lane >> 5) << 3) + elem;
    const float inv = 1.0f / sums[k >> 7];
    twT[o] = f2bf(tw[k * 128 + col] * inv);
    if (o < 384) tbs[o] = tb[o] * (1.0f / sums[o >> 7]);
}

// CSR gather of bf16 x: aggb[n][r*128+f] = bf16( sum_e ev_e * x_bf[src_e][f] );
// asum[r][n] = sum_e ev_e.  16-lane group per (r,n); 4-deep edge batching;
// NT loads for streamed edge payload; NT stores for aggb.
__global__ __launch_bounds__(256, 8)
void agg_kernel(const int* __restrict__ row_start, const int* __restrict__ bsum,
                const int2* __restrict__ edge_sorted,
                const unsigned short* __restrict__ x_bf,
                unsigned short* __restrict__ aggb, float* __restrict__ asum) {
    const int lane = threadIdx.x & 15;
    const int r = blockIdx.y;
    const int n = blockIdx.x * 16 + (threadIdx.x >> 4);
    const int beg = row_start[r * N_NODES + n] + bsum[r * NCHUNK + (n >> 10)];
    const int end = (n == N_NODES - 1)
                        ? NEDGE
                        : row_start[r * N_NODES + n + 1] + bsum[r * NCHUNK + ((n + 1) >> 10)];
    const long long* es = (const long long*)(edge_sorted + (size_t)r * NEDGE);

    float acc[8] = {0.f, 0.f, 0.f, 0.f, 0.f, 0.f, 0.f, 0.f};
    float asacc = 0.f;

    for (int i = beg; i < end; i += 4) {
        const int rem = end - i;
        long long q0, q1, q2, q3;
        q0 = __builtin_nontemporal_load(es + i);
        if (rem > 1) q1 = __builtin_nontemporal_load(es + i + 1);
        if (rem > 2) q2 = __builtin_nontemporal_load(es + i + 2);
        if (rem > 3) q3 = __builtin_nontemporal_load(es + i + 3);
        u16x8 xv0, xv1, xv2, xv3;
        xv0 = *reinterpret_cast<const u16x8*>(x_bf + (size_t)(int)q0 * FDIM + lane * 8);
        if (rem > 1) xv1 = *reinterpret_cast<const u16x8*>(x_bf + (size_t)(int)q1 * FDIM + lane * 8);
        if (rem > 2) xv2 = *reinterpret_cast<const u16x8*>(x_bf + (size_t)(int)q2 * FDIM + lane * 8);
        if (rem > 3) xv3 = *reinterpret_cast<const u16x8*>(x_bf + (size_t)(int)q3 * FDIM + lane * 8);
        {
            const float a = __int_as_float((int)(q0 >> 32));
            asacc += a;
#pragma unroll
            for (int d = 0; d < 8; ++d) acc[d] += a * bf2f(xv0[d]);
        }
        if (rem > 1) {
            const float a = __int_as_float((int)(q1 >> 32));
            asacc += a;
#pragma unroll
            for (int d = 0; d < 8; ++d) acc[d] += a * bf2f(xv1[d]);
        }
        if (rem > 2) {
            const float a = __int_as_float((int)(q2 >> 32));
            asacc += a;
#pragma unroll
            for (int d = 0; d < 8; ++d) acc[d] += a * bf2f(xv2[d]);
        }
        if (rem > 3) {
            const float a = __int_as_float((int)(q3 >> 32));
            asacc += a;
#pragma unroll
            for (int d = 0; d < 8; ++d) acc[d] += a * bf2f(xv3[d]);
        }
    }

    u16x8 o;
#pragma unroll
    for (int d = 0; d < 8; ++d) o[d] = f2bf(acc[d]);
    i32x4* dst4 = reinterpret_cast<i32x4*>(aggb + (size_t)n * 384 + r * FDIM + lane * 8);
    __builtin_nontemporal_store(*reinterpret_cast<i32x4*>(&o), dst4);
    if (lane == 0) asum[r * N_NODES + n] = asacc;
}

// out[N][128] = relu( A[N][384](bf16) @ W + asum·tbs + h_bias )
// v8: MFMA 32x32x16, barrier-free; full frag-ordered B (96 KB) in LDS.
// Grid = 256 (one block per CU); wave-major tile distribution.
// A-fragment loads for the first 4 K-steps are issued BEFORE the B-stage
// barrier so HBM/L3 latency hides under the LDS-write drain.
__global__ __launch_bounds__(1024, 4)
void gemm_kernel(const unsigned short* __restrict__ A, const unsigned short* __restrict__ Bf,
                 const float* __restrict__ asum, const float* __restrict__ tbs,
                 const float* __restrict__ h_bias, float* __restrict__ out) {
    __shared__ int4 sB[6144];  // 96 KB, frag-ordered: [ks][kk][ct][lane] x 16B
    const int tid = threadIdx.x;
    const int4* Bfv = reinterpret_cast<const int4*>(Bf);
#pragma unroll
    for (int i = 0; i < 6; ++i) sB[i * 1024 + tid] = Bfv[i * 1024 + tid];

    const int w = tid >> 6, l = tid & 63;
    const int t = w * 256 + blockIdx.x;  // tile id
    const bool active = t < NTILES;
    const int row = l & 31, hi = l >> 5;
    const int n0 = t * 32;
    const int arow = active ? (n0 + row) : 0;
    const unsigned short* aptr = A + (size_t)arow * 384 + hi * 8;

    // preload A frags for ks=0..3 before the barrier (hide B-stage drain)
    bf16x8 afr[8];
#pragma unroll
    for (int i = 0; i < 4; ++i) {
        afr[2 * i]     = *reinterpret_cast<const bf16x8*>(aptr + i * 32);
        afr[2 * i + 1] = *reinterpret_cast<const bf16x8*>(aptr + i * 32 + 16);
    }
    __syncthreads();
    if (!active) return;
    const unsigned short* sb = reinterpret_cast<const unsigned short*>(sB);

    f32x16 acc[4];
#pragma unroll
    for (int ct = 0; ct < 4; ++ct)
#pragma unroll
        for (int j = 0; j < 16; ++j) acc[ct][j] = 0.f;

#pragma unroll
    for (int ks = 0; ks < 12; ++ks) {
        const bf16x8 af0 = (ks < 4) ? afr[2 * ks]
                                    : *reinterpret_cast<const bf16x8*>(aptr + ks * 32);
        const bf16x8 af1 = (ks < 4) ? afr[2 * ks + 1]
                                    : *reinterpret_cast<const bf16x8*>(aptr + ks * 32 + 16);
        const unsigned short* sbk = sb + ks * 4096;
#pragma unroll
        for (int ct = 0; ct < 4; ++ct) {
            const bf16x8 b0 = *reinterpret_cast<const bf16x8*>(sbk + ct * 512 + l * 8);
            acc[ct] = __builtin_amdgcn_mfma_f32_32x32x16_bf16(af0, b0, acc[ct], 0, 0, 0);
        }
#pragma unroll
        for (int ct = 0; ct < 4; ++ct) {
            const bf16x8 b1 = *reinterpret_cast<const bf16x8*>(sbk + 2048 + ct * 512 + l * 8);
            acc[ct] = __builtin_amdgcn_mfma_f32_32x32x16_bf16(af1, b1, acc[ct], 0, 0, 0);
        }
    }

    // epilogue: D col = lane&31, row = (reg&3) + 8*(reg>>2) + 4*(lane>>5)
    const int col = row;  // l&31
    const float hb = h_bias[col];
    const float t0 = tbs[col], t1 = tbs[FDIM + col], t2 = tbs[2 * FDIM + col];
#pragma unroll
    for (int g = 0; g < 4; ++g) {
        const int rbase = n0 + g * 8 + hi * 4;
        float as0[4], as1[4], as2[4];
#pragma unroll
        for (int j = 0; j < 4; ++j) {
            as0[j] = asum[0 * N_NODES + rbase + j];
            as1[j] = asum[1 * N_NODES + rbase + j];
            as2[j] = asum[2 * N_NODES + rbase + j];
        }
#pragma unroll
        for (int ct = 0; ct < 4; ++ct) {
#pragma unroll
            for (int j = 0; j < 4; ++j) {
                const int r_ = rbase + j;
                float v = acc[ct][g * 4 + j] + as0[j] * t0 + as1[j] * t1 + as2[j] * t2 + hb;
                out[(size_t)r_ * FDIM + ct * 32 + col] = fmaxf(v, 0.f);
            }
        }
    }
}

extern "C" void kernel_launch(void* const* d_in, const int* in_sizes, int n_in,
                              void* d_out, int out_size, void* d_ws, size_t ws_size,
                              hipStream_t stream) {
    const float* x      = (const float*)d_in[0];
    const float* att_w  = (const float*)d_in[1];
    const float* att_b  = (const float*)d_in[2];
    const float* tw     = (const float*)d_in[3];
    const float* tb     = (const float*)d_in[4];
    const float* h_bias = (const float*)d_in[5];
    const int*   src    = (const int*)d_in[6];
    const int*   dst    = (const int*)d_in[7];
    float* out = (float*)d_out;

    float* wsf = (float*)d_ws;
    float* ps         = wsf + WS_PS;
    float* pd         = wsf + WS_PD;
    float* sums       = wsf + WS_SUMS;
    int*   count      = (int*)(wsf + WS_COUNT);
    int*   row_start  = (int*)(wsf + WS_ROWS);
    int*   bsum       = (int*)(wsf + WS_BSUM);
    int2*  edge_sorted= (int2*)(wsf + WS_ESORT);
    float* asum       = wsf + WS_ASUM;
    unsigned short* twT  = (unsigned short*)(wsf + WS_TWT);
    float* tbs        = wsf + WS_TBS;
    unsigned short* x_bf = (unsigned short*)(wsf + WS_XBF);
    unsigned short* aggb = (unsigned short*)(wsf + WS_AGGB);
    int*   rank       = (int*)(wsf + WS_RANK);

    hipMemsetAsync(count, 0, (size_t)RREL * N_NODES * sizeof(int), stream);

    proj_hist_kernel<<<PROJ_BLOCKS + HIST_BLOCKS, 256, 0, stream>>>(x, att_w, ps, pd, x_bf,
                                                                    dst, count, rank);

    scan1_kernel<<<RREL * NCHUNK, 256, 0, stream>>>(count, row_start, bsum);
    scan2_kernel<<<RREL, 256, 0, stream>>>(bsum, sums);

    fill_kernel<<<RREL * NEDGE / 256, 256, 0, stream>>>(src, dst, ps, pd, att_b,
                                                        row_start, bsum, rank,
                                                        edge_sorted, sums);

    cast_kernel<<<192, 256, 0, stream>>>(tw, tb, sums, twT, tbs);

    agg_kernel<<<dim3(N_NODES / 16, RREL), 256, 0, stream>>>(row_start, bsum, edge_sorted,
                                                             x_bf, aggb, asum);

    gemm_kernel<<<256, 1024, 0, stream>>>(aggb, twT, asum, tbs, h_bias, out);
}